// Round 1
// baseline (220.673 us; speedup 1.0000x reference)
//
#include <hip/hip_runtime.h>

// Problem constants: B=8, C=256, H=W=128, K=20
constexpr int NB   = 8;
constexpr int NC   = 256;
constexpr int NPIX = 16384;   // 128*128
constexpr int NK   = 20;
constexpr int NOUT_BBOX = 8 * 19 * 4;   // 608

// ---------------------------------------------------------------------------
// Kernel 1: per-pixel argmax over K class planes, fused with passthrough copy
// of encoded_classes into the output buffer. conn stored as uint8.
// Grid: 256 blocks x 256 threads, 2 pixels/thread (float2).
// ---------------------------------------------------------------------------
__global__ __launch_bounds__(256) void k_argmax_copy(
        const float* __restrict__ cls,
        float* __restrict__ out_copy,
        unsigned char* __restrict__ conn) {
    int t  = blockIdx.x * 256 + threadIdx.x;    // 0..65535
    int b  = t >> 13;                            // 8192 threads per batch
    int p  = (t & 8191) * 2;                     // pixel pair
    const float* base = cls      + (size_t)b * (NK * NPIX) + p;
    float*       ob   = out_copy + (size_t)b * (NK * NPIX) + p;

    float2 v0 = *(const float2*)(base);
    *(float2*)(ob) = v0;
    float m0 = v0.x, m1 = v0.y;
    int   i0 = 0,    i1 = 0;
    #pragma unroll
    for (int k = 1; k < NK; ++k) {
        float2 v = *(const float2*)(base + (size_t)k * NPIX);
        *(float2*)(ob + (size_t)k * NPIX) = v;
        if (v.x > m0) { m0 = v.x; i0 = k; }     // strict > keeps first index
        if (v.y > m1) { m1 = v.y; i1 = k; }
    }
    uchar2 cc; cc.x = (unsigned char)i0; cc.y = (unsigned char)i1;
    *(uchar2*)(conn + (size_t)b * NPIX + p) = cc;
}

// ---------------------------------------------------------------------------
// Kernel 2: segment max. One block per (b,c) pair -> no global atomics.
// Per-wave LDS accumulators (int atomicMax on float bit patterns; valid
// because we only need max(seg_max, 0) and clamp inputs to >= 0).
// Grid: 2048 blocks x 256 threads; each block streams a 64KB channel plane.
// ---------------------------------------------------------------------------
__global__ __launch_bounds__(256) void k_segmax(
        const float* __restrict__ enc,
        const unsigned char* __restrict__ conn,
        float* __restrict__ seg) {
    int bc = blockIdx.x;            // 0..2047
    int b  = bc >> 8;
    int c  = bc & 255;
    int tid  = threadIdx.x;
    int wave = tid >> 6;

    __shared__ int smax[4 * NK];
    if (tid < 4 * NK) smax[tid] = 0;     // == __float_as_int(0.0f)
    __syncthreads();

    const float*         src = enc  + ((size_t)(b * NC + c)) * NPIX;
    const unsigned char* cn  = conn + (size_t)b * NPIX;
    int* sm = smax + wave * NK;

    #pragma unroll 4
    for (int it = 0; it < 16; ++it) {
        int base = it * 1024 + tid * 4;
        float4 v  = *(const float4*)(src + base);
        uchar4 kk = *(const uchar4*)(cn + base);
        atomicMax(&sm[kk.x], __float_as_int(fmaxf(v.x, 0.0f)));
        atomicMax(&sm[kk.y], __float_as_int(fmaxf(v.y, 0.0f)));
        atomicMax(&sm[kk.z], __float_as_int(fmaxf(v.z, 0.0f)));
        atomicMax(&sm[kk.w], __float_as_int(fmaxf(v.w, 0.0f)));
    }
    __syncthreads();

    if (tid < NK) {
        int m = max(max(smax[tid],          smax[NK + tid]),
                    max(smax[2 * NK + tid], smax[3 * NK + tid]));
        // seg layout: [b][k][c], values already == max(segment_max, 0)
        seg[((size_t)b * NK + tid) * NC + c] = __int_as_float(m);
    }
}

// ---------------------------------------------------------------------------
// Kernel 3: tiny MLP + sigmoid. One block per (b,k) row.
//   hid = relu_vec @ w1^T + b1  (128 outputs, one per thread)
//   bbox = sigmoid(hid @ w2^T + b2), written only for k >= 1.
// ---------------------------------------------------------------------------
__global__ __launch_bounds__(128) void k_mlp(
        const float* __restrict__ seg,
        const float* __restrict__ w1, const float* __restrict__ b1,
        const float* __restrict__ w2, const float* __restrict__ b2,
        float* __restrict__ out) {
    int row = blockIdx.x;           // 0..159  (= b*K + k)
    int tid = threadIdx.x;          // 0..127

    __shared__ float vec[NC];
    __shared__ float hid[128];

    vec[tid]       = seg[(size_t)row * NC + tid];
    vec[tid + 128] = seg[(size_t)row * NC + tid + 128];
    __syncthreads();

    float acc = b1[tid];
    const float4* wr = (const float4*)(w1 + (size_t)tid * NC);
    #pragma unroll
    for (int c4 = 0; c4 < NC / 4; ++c4) {
        float4 w = wr[c4];
        acc += vec[c4 * 4 + 0] * w.x + vec[c4 * 4 + 1] * w.y
             + vec[c4 * 4 + 2] * w.z + vec[c4 * 4 + 3] * w.w;
    }
    hid[tid] = acc;
    __syncthreads();

    int k = row % NK;
    int b = row / NK;
    if (tid < 4 && k >= 1) {
        float a = b2[tid];
        const float* w2r = w2 + tid * 128;
        #pragma unroll
        for (int o = 0; o < 128; ++o) a += hid[o] * w2r[o];
        out[((size_t)(b * 19 + (k - 1))) * 4 + tid] = 1.0f / (1.0f + __expf(-a));
    }
}

// ---------------------------------------------------------------------------
extern "C" void kernel_launch(void* const* d_in, const int* in_sizes, int n_in,
                              void* d_out, int out_size, void* d_ws, size_t ws_size,
                              hipStream_t stream) {
    const float* encoded = (const float*)d_in[0];   // (8,256,128,128)
    const float* cls     = (const float*)d_in[1];   // (8,20,128,128)
    const float* w1      = (const float*)d_in[2];   // (128,256)
    const float* b1      = (const float*)d_in[3];   // (128,)
    const float* w2      = (const float*)d_in[4];   // (4,128)
    const float* b2      = (const float*)d_in[5];   // (4,)
    float* out = (float*)d_out;                     // [608 bbox | 8*20*128*128 copy]

    // Workspace layout: conn (uint8, 131072 B) | seg (fp32, 160*256*4 B)
    unsigned char* conn = (unsigned char*)d_ws;
    float* seg = (float*)((char*)d_ws + (size_t)NB * NPIX);

    k_argmax_copy<<<256, 256, 0, stream>>>(cls, out + NOUT_BBOX, conn);
    k_segmax<<<2048, 256, 0, stream>>>(encoded, conn, seg);
    k_mlp<<<NB * NK, 128, 0, stream>>>(seg, w1, b1, w2, b2, out);
}